// Round 21
// baseline (450.927 us; speedup 1.0000x reference)
//
#include <hip/hip_runtime.h>
#include <hip/hip_fp16.h>
#include <math.h>

// Problem constants: N=100000, E=400000, G=64, IN=8, H=4, C=64, HD=256.
// R20b: gat_aggregate with cross-batch software-pipelined gathers (batch i+1
// loads issued before batch i compute), wave-uniform nE==4 fast path, and
// nontemporal out stores (preserve L2 for xl gathers). Fix vs R20: NT store
// operand must be a native scalar/vector -> bit_cast to unsigned long long.
// Rest = R18b (fp16 chain, no-max softmax, packed-fp16 logit/butterfly/acc,
// single-term fp16-B MFMA GEMM, LDS-transpose epilogue).

#define HD 256
#define NHEAD 4
#define CH 64

typedef _Float16 half8 __attribute__((ext_vector_type(8)));
typedef _Float16 h2 __attribute__((ext_vector_type(2)));
typedef __attribute__((ext_vector_type(4))) float f32x4;

__device__ __forceinline__ h2 pack_h2(float a, float b) {
#if __has_builtin(__builtin_amdgcn_cvt_pkrtz)
    return __builtin_bit_cast(h2, __builtin_amdgcn_cvt_pkrtz(a, b));
#else
    return h2{(_Float16)a, (_Float16)b};
#endif
}

// ---------------------------------------------------------------------------
// prep_w helper: Wl,Wr [K,256] fp32 -> fp16 B-frag layout (single region).
// Lane holds B[k=(l>>4)*8+j][n=l&15] of tile (ks,ct); ct<16->Wl, else Wr.
// ---------------------------------------------------------------------------
__device__ __forceinline__ void prep_one(const float* Wl, const float* Wr,
                                         ushort* frag, int K, int t) {
    int l = t & 63;
    int ct = (t >> 6) & 31;
    int ks = t >> 11;
    int n = l & 15, q = l >> 4;
    const float* W = (ct < 16) ? Wl : Wr;
    int col = (ct & 15) * 16 + n;
    ushort* phi = frag + (size_t)t * 8;
#pragma unroll
    for (int j = 0; j < 8; ++j) {
        int k = ks * 32 + q * 8 + j;
        float wv = W[(size_t)k * 256 + col];
        phi[j] = __half_as_ushort(__float2half(wv));
    }
}

__global__ void setup_kernel(int* __restrict__ zbase, int nzero,
                             const float* __restrict__ Wl1, const float* __restrict__ Wr1,
                             ushort* __restrict__ f1,
                             const float* __restrict__ Wl2, const float* __restrict__ Wr2,
                             ushort* __restrict__ f2) {
    int i = blockIdx.x * 256 + threadIdx.x;
    if (i < nzero) {
        zbase[i] = 0;
    } else {
        int gt = i - nzero;
        if (gt < 64 * 64) prep_one(Wl1, Wr1, f1, 64, gt);
        else if (gt < 64 * 64 + 256 * 64) prep_one(Wl2, Wr2, f2, 256, gt - 64 * 64);
    }
}

// ---------------------------------------------------------------------------
// CSR build: degree histogram -> scan (2 kernels) -> scatter (packed int2).
// ---------------------------------------------------------------------------
__global__ void deg_kernel(const int* __restrict__ dst, int* __restrict__ cnt, int E) {
    int e = blockIdx.x * 256 + threadIdx.x;
    if (e < E) atomicAdd(&cnt[dst[e]], 1);
}

__global__ void scan_block(const int* __restrict__ cnt, int* __restrict__ off,
                           int* __restrict__ bsum, int N) {
    __shared__ int s[256];
    int i = blockIdx.x * 256 + threadIdx.x;
    int v = (i < N) ? cnt[i] : 0;
    s[threadIdx.x] = v;
    __syncthreads();
    for (int d = 1; d < 256; d <<= 1) {
        int t = 0;
        if (threadIdx.x >= d) t = s[threadIdx.x - d];
        __syncthreads();
        s[threadIdx.x] += t;
        __syncthreads();
    }
    if (i < N) off[i + 1] = s[threadIdx.x];
    if (threadIdx.x == 255) bsum[blockIdx.x] = s[255];
    if (blockIdx.x == 0 && threadIdx.x == 0) off[0] = 0;
}

__global__ void scan_add2(int* __restrict__ off, const int* __restrict__ bsum, int N) {
    __shared__ int red[4];
    int b = blockIdx.x;
    int s = 0;
    for (int i = threadIdx.x; i < b; i += 256) s += bsum[i];
    for (int o = 32; o > 0; o >>= 1) s += __shfl_xor(s, o);
    if ((threadIdx.x & 63) == 0) red[threadIdx.x >> 6] = s;
    __syncthreads();
    int prefix = red[0] + red[1] + red[2] + red[3];
    int i = b * 256 + threadIdx.x;
    if (i < N) off[i + 1] += prefix;
}

__global__ void scatter_kernel(const int* __restrict__ dst, const int* __restrict__ src,
                               const float* __restrict__ eattr, const int* __restrict__ off,
                               int* __restrict__ cur, int2* __restrict__ edata, int E) {
    int e = blockIdx.x * 256 + threadIdx.x;
    if (e < E) {
        int d = dst[e];
        int p = atomicAdd(&cur[d], 1);
        edata[off[d] + p] = make_int2(src[e], __float_as_int(eattr[e]));
    }
}

// ---------------------------------------------------------------------------
// FP16 MFMA dual GEMM (R17): 512 thr (8 waves), 64 rows, single staging
// barrier; A fp16 exact, B fp16 single-term; LDS-transpose epilogue
// (stride 260) -> uint4 row stores. FUSE_ENC: A is x[N,8] fp32.
// outR may alias A (A fully consumed at staging).
// ---------------------------------------------------------------------------
template <int K, bool FUSE_ENC>
__global__ __launch_bounds__(512, 4) void gemm_mfma(
    const void* Av, const float* __restrict__ Wenc, const float* __restrict__ benc,
    const ushort* __restrict__ Bfrag,
    const float* __restrict__ bl, const float* __restrict__ br,
    ushort* __restrict__ outL, ushort* outR, int N) {
    constexpr int KS = K / 32;
    constexpr int C4 = K / 4;
    constexpr int LC4 = (K == 256) ? 6 : 4;
    constexpr int FRAG_SHORTS = KS * 4 * 64 * 8;
    constexpr int TB_STRIDE = 260;
    constexpr int SH_BYTES = (FRAG_SHORTS * 2 > 64 * TB_STRIDE * 2)
                                 ? FRAG_SHORTS * 2 : 64 * TB_STRIDE * 2;
    __shared__ __align__(16) char shraw[SH_BYTES];
    ushort* frag = (ushort*)shraw;
    ushort* tbuf = (ushort*)shraw;

    const int t = threadIdx.x;
    const int row0 = blockIdx.x * 64;
    const float* Ax = (const float*)Av;
    const ushort* Ahalf = (const ushort*)Av;

#pragma unroll
    for (int it = 0; it < (64 * C4) / 512; ++it) {
        int jj = it * 512 + t;
        int m = jj & 15;
        int c4 = (jj >> 4) & (C4 - 1);
        int rg = jj >> (4 + LC4);
        int row = row0 + rg * 16 + m;
        ushort4 sv = make_ushort4(0, 0, 0, 0);
        if constexpr (FUSE_ENC) {
            if (row < N) {
                float4 xa = *(const float4*)(Ax + (size_t)row * 8);
                float4 xb = *(const float4*)(Ax + (size_t)row * 8 + 4);
                float xrv[8] = {xa.x, xa.y, xa.z, xa.w, xb.x, xb.y, xb.z, xb.w};
                ushort o[4];
#pragma unroll
                for (int j = 0; j < 4; ++j) {
                    int c = c4 * 4 + j;
                    float a = benc[c];
#pragma unroll
                    for (int u = 0; u < 8; ++u) a = fmaf(xrv[u], Wenc[u * 64 + c], a);
                    o[j] = __half_as_ushort(__float2half(fmaxf(a, 0.f)));
                }
                sv = make_ushort4(o[0], o[1], o[2], o[3]);
            }
        } else {
            if (row < N) sv = *(const ushort4*)(Ahalf + (size_t)row * K + c4 * 4);
        }
        int c = c4 * 4;
        int ks = c >> 5, q = (c >> 3) & 3, jb = c & 7;
        int cell = (ks * 4 + rg) * 64 + m + 16 * q;
        *(ushort4*)(frag + cell * 8 + jb) = sv;
    }
    __syncthreads();

    const int w = t >> 6, l = t & 63;
    const int ct0 = w * 4;

    f32x4 acc[4][4];
#pragma unroll
    for (int rt = 0; rt < 4; ++rt)
#pragma unroll
        for (int c = 0; c < 4; ++c) acc[rt][c] = (f32x4){0.f, 0.f, 0.f, 0.f};

#pragma unroll
    for (int ks = 0; ks < KS; ++ks) {
        half8 a[4];
#pragma unroll
        for (int rt = 0; rt < 4; ++rt) {
            int cell = (ks * 4 + rt) * 64 + l;
            a[rt] = *(const half8*)(frag + cell * 8);
        }
#pragma unroll
        for (int c = 0; c < 4; ++c) {
            size_t e = ((size_t)(ks * 32 + ct0 + c) * 64 + l) * 8;
            half8 bh = *(const half8*)(Bfrag + e);
#pragma unroll
            for (int rt = 0; rt < 4; ++rt)
                acc[rt][c] = __builtin_amdgcn_mfma_f32_16x16x32_f16(a[rt], bh, acc[rt][c], 0, 0, 0);
        }
    }

    const int m = l & 15, q = l >> 4;
#pragma unroll
    for (int half = 0; half < 2; ++half) {
        __syncthreads();
        if ((w >> 2) == half) {
            const float* bias = half ? br : bl;
#pragma unroll
            for (int c = 0; c < 4; ++c) {
                int col = ((ct0 + c) & 15) * 16 + m;
                float bb = bias[col];
#pragma unroll
                for (int rt = 0; rt < 4; ++rt)
#pragma unroll
                    for (int r = 0; r < 4; ++r)
                        tbuf[(rt * 16 + q * 4 + r) * TB_STRIDE + col] =
                            __half_as_ushort(__float2half(acc[rt][c][r] + bb));
            }
        }
        __syncthreads();
        ushort* outp = half ? outR : outL;
#pragma unroll
        for (int it = 0; it < 4; ++it) {
            int jj = it * 512 + t;
            int row = jj >> 5;
            int ch = jj & 31;
            int grow = row0 + row;
            if (grow < N) {
                uint2 a0 = *(const uint2*)(tbuf + row * TB_STRIDE + ch * 8);
                uint2 a1 = *(const uint2*)(tbuf + row * TB_STRIDE + ch * 8 + 4);
                *(uint4*)(outp + (size_t)grow * 256 + ch * 8) =
                    make_uint4(a0.x, a0.y, a1.x, a1.y);
            }
        }
    }
}

// ---------------------------------------------------------------------------
// GATv2 aggregation (R20b): wave per node; lane = head*16 + quarter owns 4
// channels (2x half2). Packed fp16 logit + fdot2 att-dot; no-max softmax;
// packed butterfly; packed acc. Cross-batch pipelining: batch i+1's gathers
// issued before batch i's compute. nE==4 fast path skips masking.
// Nontemporal out stores (preserve L2 for gathers). out may ALIAS xr.
// ---------------------------------------------------------------------------
__global__ __launch_bounds__(256) void gat_aggregate(
    const ushort* __restrict__ xl, const ushort* xr,
    const int* __restrict__ off, const int2* __restrict__ edata,
    const float* __restrict__ We, const float* __restrict__ att,
    const float* __restrict__ bias, ushort* out, int N) {
    int node = blockIdx.x * 4 + (threadIdx.x >> 6);
    if (node >= N) return;
    int lane = threadIdx.x & 63;
    int cbase = (lane >> 4) * 64 + (lane & 15) * 4;

    float4 wef = *(const float4*)(We + cbase);
    float4 atf = *(const float4*)(att + cbase);
    h2 we_lo = {(_Float16)wef.x, (_Float16)wef.y};
    h2 we_hi = {(_Float16)wef.z, (_Float16)wef.w};
    h2 at_lo = {(_Float16)atf.x, (_Float16)atf.y};
    h2 at_hi = {(_Float16)atf.z, (_Float16)atf.w};
    size_t nb = (size_t)node * HD;
    uint2 xru = *(const uint2*)(xr + nb + cbase);
    h2 xr_lo = __builtin_bit_cast(h2, xru.x);
    h2 xr_hi = __builtin_bit_cast(h2, xru.y);
    float4 b4 = *(const float4*)(bias + cbase);
    const h2 c02 = {(_Float16)0.2f, (_Float16)0.2f};
    const h2 z2 = {(_Float16)0.f, (_Float16)0.f};

    float l = 0.f;
    h2 acc_lo = z2, acc_hi = z2;

    int s0i = off[node], s1i = off[node + 1];
    int t = s0i;
    int nE = s1i - t;
    if (nE > 4) nE = 4;

    h2 xlo[4], xhi[4];
    float eac[4];
    // batch 0: indices + gathers
    {
        int jj[4];
#pragma unroll
        for (int u = 0; u < 4; ++u) {
            int2 ed = (u < nE) ? edata[t + u] : make_int2(0, 0);
            jj[u] = ed.x;
            eac[u] = __int_as_float(ed.y);
        }
#pragma unroll
        for (int u = 0; u < 4; ++u) {
            xlo[u] = z2; xhi[u] = z2;
            if (u < nE) {
                uint2 xu = *(const uint2*)(xl + (size_t)jj[u] * HD + cbase);
                xlo[u] = __builtin_bit_cast(h2, xu.x);
                xhi[u] = __builtin_bit_cast(h2, xu.y);
            }
        }
    }

    while (t < s1i) {
        int tn = t + 4;
        int nEn = s1i - tn;
        if (nEn < 0) nEn = 0;
        if (nEn > 4) nEn = 4;
        // issue NEXT batch's index loads + gathers before computing current
        h2 nxlo[4], nxhi[4];
        float nea[4];
        if (nEn > 0) {
            int jj[4];
#pragma unroll
            for (int u = 0; u < 4; ++u) {
                int2 ed = (u < nEn) ? edata[tn + u] : make_int2(0, 0);
                jj[u] = ed.x;
                nea[u] = __int_as_float(ed.y);
            }
#pragma unroll
            for (int u = 0; u < 4; ++u) {
                nxlo[u] = z2; nxhi[u] = z2;
                if (u < nEn) {
                    uint2 xu = *(const uint2*)(xl + (size_t)jj[u] * HD + cbase);
                    nxlo[u] = __builtin_bit_cast(h2, xu.x);
                    nxhi[u] = __builtin_bit_cast(h2, xu.y);
                }
            }
        } else {
#pragma unroll
            for (int u = 0; u < 4; ++u) { nxlo[u] = z2; nxhi[u] = z2; nea[u] = 0.f; }
        }

        // ---- compute current batch ----
        float rr[4];
#pragma unroll
        for (int u = 0; u < 4; ++u) {
            _Float16 eh = (_Float16)eac[u];
            h2 e2 = {eh, eh};
            h2 s0 = e2 * we_lo + (xlo[u] + xr_lo);
            h2 s1 = e2 * we_hi + (xhi[u] + xr_hi);
            s0 = __builtin_elementwise_max(s0, z2) + __builtin_elementwise_min(s0, z2) * c02;
            s1 = __builtin_elementwise_max(s1, z2) + __builtin_elementwise_min(s1, z2) * c02;
            float v;
#if __has_builtin(__builtin_amdgcn_fdot2)
            v = __builtin_amdgcn_fdot2(__builtin_bit_cast(__fp16 __attribute__((ext_vector_type(2))), at_lo),
                                       __builtin_bit_cast(__fp16 __attribute__((ext_vector_type(2))), s0),
                                       0.f, false);
            v = __builtin_amdgcn_fdot2(__builtin_bit_cast(__fp16 __attribute__((ext_vector_type(2))), at_hi),
                                       __builtin_bit_cast(__fp16 __attribute__((ext_vector_type(2))), s1),
                                       v, false);
#else
            v = (float)at_lo.x * (float)s0.x + (float)at_lo.y * (float)s0.y
              + (float)at_hi.x * (float)s1.x + (float)at_hi.y * (float)s1.y;
#endif
            rr[u] = v;
        }
        // packed butterfly over the 16-lane quadrant (2 edges per shuffle)
        h2 r01 = pack_h2(rr[0], rr[1]);
        h2 r23 = pack_h2(rr[2], rr[3]);
#pragma unroll
        for (int o = 1; o <= 8; o <<= 1) {
            int v01 = __shfl_xor(__builtin_bit_cast(int, r01), o);
            int v23 = __shfl_xor(__builtin_bit_cast(int, r23), o);
            r01 = r01 + __builtin_bit_cast(h2, v01);
            r23 = r23 + __builtin_bit_cast(h2, v23);
        }
        float r0 = (float)r01.x, r1 = (float)r01.y;
        float r2 = (float)r23.x, r3 = (float)r23.y;
        if (nE < 4) {                    // wave-uniform fast path
            if (1 >= nE) r1 = -1e30f;
            if (2 >= nE) r2 = -1e30f;
            if (3 >= nE) r3 = -1e30f;
        }
        float p0 = __expf(r0);
        float p1 = __expf(r1);
        float p2 = __expf(r2);
        float p3 = __expf(r3);
        l += (p0 + p1) + (p2 + p3);
        h2 ph0 = pack_h2(p0, p0);
        h2 ph1 = pack_h2(p1, p1);
        h2 ph2 = pack_h2(p2, p2);
        h2 ph3 = pack_h2(p3, p3);
        acc_lo = ph0 * xlo[0] + acc_lo;
        acc_hi = ph0 * xhi[0] + acc_hi;
        acc_lo = ph1 * xlo[1] + acc_lo;
        acc_hi = ph1 * xhi[1] + acc_hi;
        acc_lo = ph2 * xlo[2] + acc_lo;
        acc_hi = ph2 * xhi[2] + acc_hi;
        acc_lo = ph3 * xlo[3] + acc_lo;
        acc_hi = ph3 * xhi[3] + acc_hi;

        // rotate next -> current
#pragma unroll
        for (int u = 0; u < 4; ++u) {
            xlo[u] = nxlo[u];
            xhi[u] = nxhi[u];
            eac[u] = nea[u];
        }
        t = tn;
        nE = nEn;
    }

    float inv = 1.f / (l + 1e-16f);
    float ax = (float)acc_lo.x, ay = (float)acc_lo.y;
    float az = (float)acc_hi.x, aw = (float)acc_hi.y;
    ushort4 o;
    o.x = __half_as_ushort(__float2half(fmaxf(fmaf(ax, inv, b4.x), 0.f)));
    o.y = __half_as_ushort(__float2half(fmaxf(fmaf(ay, inv, b4.y), 0.f)));
    o.z = __half_as_ushort(__float2half(fmaxf(fmaf(az, inv, b4.z), 0.f)));
    o.w = __half_as_ushort(__float2half(fmaxf(fmaf(aw, inv, b4.w), 0.f)));
    __builtin_nontemporal_store(__builtin_bit_cast(unsigned long long, o),
                                (unsigned long long*)(out + nb + cbase));
}

// ---------------------------------------------------------------------------
__device__ __forceinline__ int lowerb(const int* b, int n, int v) {
    int lo = 0, hi = n;
    while (lo < hi) {
        int mid = (lo + hi) >> 1;
        if (b[mid] < v) lo = mid + 1; else hi = mid;
    }
    return lo;
}

__global__ void pool_kernel(const ushort* __restrict__ h, const int* __restrict__ batch,
                            float* __restrict__ pooled, float* __restrict__ gcnt, int N) {
    int g = blockIdx.x >> 3, part = blockIdx.x & 7;
    int start = lowerb(batch, N, g);
    int end = lowerb(batch, N, g + 1);
    int rows = end - start;
    int r0 = start + (int)((long long)rows * part / 8);
    int r1 = start + (int)((long long)rows * (part + 1) / 8);
    int c = threadIdx.x;
    float s = 0.f;
    for (int r = r0; r < r1; ++r)
        s += __half2float(__ushort_as_half(h[(size_t)r * HD + c]));
    atomicAdd(&pooled[g * HD + c], s);
    if (part == 0 && c == 0) gcnt[g] = (float)rows;
}

// ---------------------------------------------------------------------------
__global__ void mlp_kernel(const float* __restrict__ pooled, const float* __restrict__ gcnt,
                           const float* __restrict__ W_p1, const float* __restrict__ b_p1,
                           const float* __restrict__ ln_g, const float* __restrict__ ln_b,
                           const float* __restrict__ W_p2, const float* __restrict__ b_p2,
                           const float* __restrict__ W_head, const float* __restrict__ b_head,
                           float* __restrict__ out) {
    int g = blockIdx.x;
    int j = threadIdx.x;
    __shared__ float sh[128];
    __shared__ float red[2];

    float inv = 1.f / fmaxf(gcnt[g], 1.f);
    float v = b_p1[j];
    for (int k = 0; k < 256; ++k) v = fmaf(pooled[g * 256 + k] * inv, W_p1[k * 128 + j], v);

    float s = v;
    for (int o = 32; o > 0; o >>= 1) s += __shfl_xor(s, o);
    if ((j & 63) == 0) red[j >> 6] = s;
    __syncthreads();
    float mu = (red[0] + red[1]) * (1.f / 128.f);
    float d = v - mu;
    float s2 = d * d;
    for (int o = 32; o > 0; o >>= 1) s2 += __shfl_xor(s2, o);
    __syncthreads();
    if ((j & 63) == 0) red[j >> 6] = s2;
    __syncthreads();
    float var = (red[0] + red[1]) * (1.f / 128.f);

    float p = d * rsqrtf(var + 1e-5f) * ln_g[j] + ln_b[j];
    sh[j] = fmaxf(p, 0.f);
    __syncthreads();

    if (j < 64) {
        float q = b_p2[j];
        for (int k = 0; k < 128; ++k) q = fmaf(sh[k], W_p2[k * 64 + j], q);
        q = fmaxf(q, 0.f);
        float t = q * W_head[j];
        for (int o = 32; o > 0; o >>= 1) t += __shfl_xor(t, o);
        if (j == 0) out[g] = t + b_head[0];
    }
}

// ---------------------------------------------------------------------------
extern "C" void kernel_launch(void* const* d_in, const int* in_sizes, int n_in,
                              void* d_out, int out_size, void* d_ws, size_t ws_size,
                              hipStream_t stream) {
    const float* x      = (const float*)d_in[0];
    const float* eattr  = (const float*)d_in[1];
    const int*   src    = (const int*)d_in[2];
    const int*   dst    = (const int*)d_in[3];
    const int*   batch  = (const int*)d_in[4];
    const float* W_enc  = (const float*)d_in[5];
    const float* b_enc  = (const float*)d_in[6];
    const float* g1_Wl  = (const float*)d_in[7];
    const float* g1_bl  = (const float*)d_in[8];
    const float* g1_Wr  = (const float*)d_in[9];
    const float* g1_br  = (const float*)d_in[10];
    const float* g1_We  = (const float*)d_in[11];
    const float* g1_att = (const float*)d_in[12];
    const float* g1_bias= (const float*)d_in[13];
    const float* g2_Wl  = (const float*)d_in[14];
    const float* g2_bl  = (const float*)d_in[15];
    const float* g2_Wr  = (const float*)d_in[16];
    const float* g2_br  = (const float*)d_in[17];
    const float* g2_We  = (const float*)d_in[18];
    const float* g2_att = (const float*)d_in[19];
    const float* g2_bias= (const float*)d_in[20];
    const float* W_p1   = (const float*)d_in[21];
    const float* b_p1   = (const float*)d_in[22];
    const float* ln_g   = (const float*)d_in[23];
    const float* ln_b   = (const float*)d_in[24];
    const float* W_p2   = (const float*)d_in[25];
    const float* b_p2   = (const float*)d_in[26];
    const float* W_head = (const float*)d_in[27];
    const float* b_head = (const float*)d_in[28];

    const int N = in_sizes[0] / 8;   // 100000
    const int E = in_sizes[2];       // 400000

    // workspace layout (~114 MB)
    char* p = (char*)d_ws;
    auto alloc = [&](size_t bytes) -> void* {
        void* r = (void*)p;
        p += (bytes + 255) & ~(size_t)255;
        return r;
    };
    ushort* bufA   = (ushort*)alloc((size_t)N * HD * 2);  // XR / h fp16 (in-place)
    ushort* bufXL  = (ushort*)alloc((size_t)N * HD * 2);  // XL fp16 (gather target)
    // contiguous zero region: cnt, cur, pooled
    int*    cnt    = (int*)alloc((size_t)N * 4);
    int*    curp   = (int*)alloc((size_t)N * 4);
    float*  pooled = (float*)alloc(64 * HD * 4);
    char*   zend   = p;
    int*    off    = (int*)alloc((size_t)(N + 1) * 4);
    int2*   edata  = (int2*)alloc((size_t)E * 8);         // (src, eattr) packed
    const int nb   = (N + 255) / 256;
    int*    bsum   = (int*)alloc((size_t)nb * 4);
    float*  gcnt   = (float*)alloc(64 * 4);
    ushort* wfrag1 = (ushort*)alloc((size_t)64 * 64 * 16 * 2);   // K=64, single region
    ushort* wfrag2 = (ushort*)alloc((size_t)256 * 64 * 16 * 2);  // K=256, single region

    const int nzero = (int)(((char*)zend - (char*)cnt) / 4);
    const int nsetup = nzero + 64 * 64 + 256 * 64;

    // ---- setup: zero cnt/cur/pooled + build both fp16 B-frag files ----
    setup_kernel<<<(nsetup + 255) / 256, 256, 0, stream>>>(
        cnt, nzero, g1_Wl, g1_Wr, wfrag1, g2_Wl, g2_Wr, wfrag2);

    // ---- CSR by dst ----
    deg_kernel<<<(E + 255) / 256, 256, 0, stream>>>(dst, cnt, E);
    scan_block<<<nb, 256, 0, stream>>>(cnt, off, bsum, N);
    scan_add2<<<nb, 256, 0, stream>>>(off, bsum, N);
    scatter_kernel<<<(E + 255) / 256, 256, 0, stream>>>(dst, src, eattr, off, curp,
                                                        edata, E);

    const int gblocks = (N + 63) / 64;
    const int ablocks = (N + 3) / 4;

    // ---- GAT layer 1 (encoder fused into staging): x -> XL(fp16), XR(fp16)
    gemm_mfma<64, true><<<gblocks, 512, 0, stream>>>(
        x, W_enc, b_enc, wfrag1, g1_bl, g1_br, bufXL, bufA, N);
    gat_aggregate<<<ablocks, 256, 0, stream>>>(
        bufXL, bufA, off, edata, g1_We, g1_att, g1_bias, bufA, N);

    // ---- GAT layer 2: h1(fp16) -> XL(fp16), XR in-place(fp16); aggregate
    gemm_mfma<256, false><<<gblocks, 512, 0, stream>>>(
        bufA, nullptr, nullptr, wfrag2, g2_bl, g2_br, bufXL, bufA, N);
    gat_aggregate<<<ablocks, 256, 0, stream>>>(
        bufXL, bufA, off, edata, g2_We, g2_att, g2_bias, bufA, N);

    // ---- pool + MLP head ----
    pool_kernel<<<64 * 8, 256, 0, stream>>>(bufA, batch, pooled, gcnt, N);
    mlp_kernel<<<64, 128, 0, stream>>>(pooled, gcnt, W_p1, b_p1, ln_g, ln_b,
                                       W_p2, b_p2, W_head, b_head, (float*)d_out);
}